// Round 4
// baseline (444.608 us; speedup 1.0000x reference)
//
#include <hip/hip_runtime.h>
#include <math.h>

#define BB   4
#define CIN  64
#define CMID 32
#define HS   96
#define WS   96
#define H2   48
#define W2   48
#define H4   24
#define W4   24
#define N2   (H2*W2)   // 2304 distinct queries
#define M4   (H4*W4)   // 576 distinct keys

// ---------------------------------------------------------------------------
// K1: 3x3 stride-2 pad-1 convs, uniform blocks, ci-chunk = 8 (LDS 25.9KB).
// Block: bx = p*2+half (p = out-row pair, half = 32-ci half), b, cz.
// 128 threads: c16 = tid&15 (co = c16, c16+16), g = tid>>4 (6 cols).
//  cz=0: theta partial -> Ptheta[half][b][n][32c]   (bias added in attn)
//  cz=1,2: phi partial -> Pphi[half][brn][b][c][n]  (bias added in phipool)
// ---------------------------------------------------------------------------
__global__ __launch_bounds__(128) void conv3x3_kernel(
    const float* __restrict__ x, const float* __restrict__ x_pan,
    const float* __restrict__ theta_w, const float* __restrict__ phi_w,
    const float* __restrict__ phi_pan_w,
    float* __restrict__ Ptheta, float* __restrict__ Pphi)
{
    const int bx = blockIdx.x;   // 0..47
    const int b  = blockIdx.y;
    const int cz = blockIdx.z;

    __shared__ __align__(16) float xs[8][5][104];   // 16.6 KB
    __shared__ float wsm[8][9][32];                 //  9.2 KB

    const int tid = threadIdx.x;
    const int c16 = tid & 15;
    const int g   = tid >> 4;        // 0..7

    const float* xin = (cz == 2) ? x_pan : x;
    const float* wgt = (cz == 0) ? theta_w : (cz == 1 ? phi_w : phi_pan_w);

    const int p    = bx >> 1;
    const int half = bx & 1;
    const int row0 = 4*p - 1;

    float acc[2][2][6];              // [co sel][out row][col]
    #pragma unroll
    for (int u = 0; u < 2; ++u)
        #pragma unroll
        for (int o = 0; o < 2; ++o)
            #pragma unroll
            for (int j = 0; j < 6; ++j) acc[u][o][j] = 0.f;

    for (int chunk = 0; chunk < 4; ++chunk) {
        const int ci0 = half*32 + chunk*8;
        __syncthreads();
        // stage x: 8 ci x 5 rows x 26 float4 (cols -8..95; k<2 are zero pads)
        for (int u = tid; u < 8*5*26; u += 128) {
            int ci = u / 130, rem = u % 130, rr = rem / 26, k = rem % 26;
            int row = row0 + rr;
            float4 v = {0.f,0.f,0.f,0.f};
            if (row >= 0 && row < HS && k >= 2)
                v = *(const float4*)&xin[((b*CIN + ci0 + ci)*HS + row)*WS + 4*k - 8];
            *(float4*)&xs[ci][rr][4*k] = v;
        }
        // stage weights: 18 float4 per co (8ci*9 = 72 floats), scatter
        for (int u = tid; u < 576; u += 128) {
            int c2 = u / 18, f = u % 18;
            float4 wv = *(const float4*)&wgt[c2*576 + ci0*9 + 4*f];
            int lin = 4*f;
            wsm[(lin  )/9][(lin  )%9][c2] = wv.x;
            wsm[(lin+1)/9][(lin+1)%9][c2] = wv.y;
            wsm[(lin+2)/9][(lin+2)%9][c2] = wv.z;
            wsm[(lin+3)/9][(lin+3)%9][c2] = wv.w;
        }
        __syncthreads();

        for (int ci = 0; ci < 8; ++ci) {
            float w9a[9], w9b[9];
            #pragma unroll
            for (int kk = 0; kk < 9; ++kk) {
                w9a[kk] = wsm[ci][kk][c16];
                w9b[kk] = wsm[ci][kk][c16 + 16];
            }
            #pragma unroll
            for (int rr = 0; rr < 5; ++rr) {
                const float4* xr = (const float4*)&xs[ci][rr][12*g + 4];
                float4 t0 = xr[0], t1 = xr[1], t2 = xr[2], t3 = xr[3];
                float xv[16] = {t0.x,t0.y,t0.z,t0.w, t1.x,t1.y,t1.z,t1.w,
                                t2.x,t2.y,t2.z,t2.w, t3.x,t3.y,t3.z,t3.w};
                if (rr <= 2) {
                    #pragma unroll
                    for (int j = 0; j < 6; ++j)
                        #pragma unroll
                        for (int kw = 0; kw < 3; ++kw) {
                            float xvv = xv[3 + 2*j + kw];
                            acc[0][0][j] += w9a[rr*3+kw] * xvv;
                            acc[1][0][j] += w9b[rr*3+kw] * xvv;
                        }
                }
                if (rr >= 2) {
                    #pragma unroll
                    for (int j = 0; j < 6; ++j)
                        #pragma unroll
                        for (int kw = 0; kw < 3; ++kw) {
                            float xvv = xv[3 + 2*j + kw];
                            acc[0][1][j] += w9a[(rr-2)*3+kw] * xvv;
                            acc[1][1][j] += w9b[(rr-2)*3+kw] * xvv;
                        }
                }
            }
        }
    }

    if (cz == 0) {
        #pragma unroll
        for (int u = 0; u < 2; ++u)
            #pragma unroll
            for (int o = 0; o < 2; ++o)
                #pragma unroll
                for (int j = 0; j < 6; ++j) {
                    int n = (2*p + o)*48 + 6*g + j;
                    Ptheta[((size_t)(half*4 + b)*N2 + n)*32 + c16 + 16*u] = acc[u][o][j];
                }
    } else {
        const int brn = cz - 1;
        #pragma unroll
        for (int u = 0; u < 2; ++u) {
            float* Pb = Pphi + (size_t)(((half*2 + brn)*4 + b)*32 + c16 + 16*u)*N2;
            #pragma unroll
            for (int o = 0; o < 2; ++o)
                #pragma unroll
                for (int j = 0; j < 6; ++j)
                    Pb[(2*p + o)*48 + 6*g + j] = acc[u][o][j];
        }
    }
}

// ---------------------------------------------------------------------------
// K1b: combine the two ci-halves of phi conv, 2x2 maxpool, +bias.
// Output Kp in [bb][k][c] layout (key-major for attn phase 1).
// ---------------------------------------------------------------------------
__global__ __launch_bounds__(256) void phipool_kernel(
    const float* __restrict__ Pphi,
    const float* __restrict__ phi_b, const float* __restrict__ phi_pan_b,
    float* __restrict__ Kp)
{
    const int o = blockIdx.x*256 + threadIdx.x;   // linear over [br][b][co][k]
    const int br   = o / 73728;
    const int rem  = o % 73728;
    const int b    = rem / 18432;
    const int rem2 = rem % 18432;
    const int co   = rem2 / 576;
    const int k    = rem2 % 576;
    const int pr   = k / 24, pc = k % 24;

    const int h1 = 2*4*32*N2;
    const int base = (((br*4 + b)*32 + co)*48 + 2*pr)*48 + 2*pc;
    float2 a0 = *(const float2*)&Pphi[base];
    float2 a1 = *(const float2*)&Pphi[base + 48];
    float2 c0 = *(const float2*)&Pphi[h1 + base];
    float2 c1 = *(const float2*)&Pphi[h1 + base + 48];
    float v00 = a0.x + c0.x, v01 = a0.y + c0.y;
    float v10 = a1.x + c1.x, v11 = a1.y + c1.y;
    float bv = (br ? phi_pan_b : phi_b)[co];
    Kp[((size_t)(br*4 + b)*576 + k)*32 + co] =
        fmaxf(fmaxf(v00, v01), fmaxf(v10, v11)) + bv;
}

// ---------------------------------------------------------------------------
// K2: V = avgpool2(maxpool2(conv1x1(x))), output [bb][c][k] (c-major rows
// contiguous over k, for attn phase-2 float4 reads).
// ---------------------------------------------------------------------------
__global__ __launch_bounds__(384) void gconv_kernel(
    const float* __restrict__ x, const float* __restrict__ x_pan,
    const float* __restrict__ g_w, const float* __restrict__ g_b,
    const float* __restrict__ g_pan_w, const float* __restrict__ g_pan_b,
    float* __restrict__ Vt)
{
    const int r4 = blockIdx.x;      // 0..23
    const int ch = blockIdx.y;      // 0..1
    const int bb = blockIdx.z;      // 0..7
    const int br = bb >> 2, b = bb & 3;
    const float* xin = br ? x_pan : x;
    const float* wg  = br ? g_pan_w : g_w;

    __shared__ __align__(16) float xs[32][4][48];
    __shared__ float wl[64*33];
    const int tid = threadIdx.x;
    for (int u = tid; u < 2048; u += 384) {
        int c2 = u >> 6, ci = u & 63;
        wl[ci*33 + c2] = wg[u];
    }

    const int c  = tid & 31;
    const int sl = tid >> 5;        // 0..11
    float4 ac0 = {0,0,0,0}, ac1 = {0,0,0,0}, ac2 = {0,0,0,0}, ac3 = {0,0,0,0};

    for (int ci0 = 0; ci0 < 64; ci0 += 32) {
        __syncthreads();
        for (int u = tid; u < 32*4*12; u += 384) {
            int ci = u / 48, rem = u % 48, r = rem / 12, k = rem % 12;
            *(float4*)&xs[ci][r][4*k] =
                *(const float4*)&xin[((b*64 + ci0 + ci)*96 + 4*r4 + r)*96 + ch*48 + 4*k];
        }
        __syncthreads();
        for (int ci = 0; ci < 32; ++ci) {
            const float wv = wl[(ci0 + ci)*33 + c];
            float4 x0 = *(const float4*)&xs[ci][0][4*sl];
            float4 x1 = *(const float4*)&xs[ci][1][4*sl];
            float4 x2 = *(const float4*)&xs[ci][2][4*sl];
            float4 x3 = *(const float4*)&xs[ci][3][4*sl];
            ac0.x += wv*x0.x; ac0.y += wv*x0.y; ac0.z += wv*x0.z; ac0.w += wv*x0.w;
            ac1.x += wv*x1.x; ac1.y += wv*x1.y; ac1.z += wv*x1.z; ac1.w += wv*x1.w;
            ac2.x += wv*x2.x; ac2.y += wv*x2.y; ac2.z += wv*x2.z; ac2.w += wv*x2.w;
            ac3.x += wv*x3.x; ac3.y += wv*x3.y; ac3.z += wv*x3.z; ac3.w += wv*x3.w;
        }
    }
    float m00 = fmaxf(fmaxf(ac0.x, ac0.y), fmaxf(ac1.x, ac1.y));
    float m01 = fmaxf(fmaxf(ac0.z, ac0.w), fmaxf(ac1.z, ac1.w));
    float m10 = fmaxf(fmaxf(ac2.x, ac2.y), fmaxf(ac3.x, ac3.y));
    float m11 = fmaxf(fmaxf(ac2.z, ac2.w), fmaxf(ac3.z, ac3.w));
    float bv = (br ? g_pan_b : g_b)[c];
    const int k = r4*24 + ch*12 + sl;
    Vt[((size_t)bb*32 + c)*576 + k] = 0.25f*(m00+m01+m10+m11) + bv;
}

// ---------------------------------------------------------------------------
// K3: attention + fused W-conv + BN partials. Block (qt, bb): 16 q x 576 k,
// 576 threads (9 waves). Phase1: lane = key, K in regs, Q broadcast from LDS,
// scores -> Pt LDS. Phase1.5: exact softmax (max/exp/z) on Pt rows.
// Phase2: AV dots (Pt broadcast x V[c][k] float4). Phase3: W-conv + stats.
// No atomics: per-block BN partials to Pp1/Pp2.
// ---------------------------------------------------------------------------
__global__ __launch_bounds__(576, 5) void attn_kernel(
    const float* __restrict__ Ptheta, const float* __restrict__ theta_b,
    const float* __restrict__ Kp, const float* __restrict__ Vt,
    const float* __restrict__ W_w, const float* __restrict__ W_b,
    const float* __restrict__ Wp_w, const float* __restrict__ Wp_b,
    float* __restrict__ zbuf, float* __restrict__ Pp1, float* __restrict__ Pp2)
{
    const int qt = blockIdx.x;      // 0..143
    const int bb = blockIdx.y;      // 0..7
    const int b  = bb & 3;
    const int br = bb >> 2;
    const int q0 = qt*16;

    __shared__ __align__(16) float Pt[16*580];   // scores, stride 580
    __shared__ __align__(16) float Qs[16*36];
    __shared__ float ybuf[16*36];
    __shared__ float Wt[32*64];                  // W transposed [c][o]
    __shared__ float zinv[16];
    __shared__ float s1b[512], s2b[512];

    const int tid = threadIdx.x;

    // ---- stage Q (= P0+P1+bias) and Wt ----
    if (tid < 512) {
        const int q = tid >> 5, c = tid & 31;
        Qs[q*36 + c] = Ptheta[((size_t)b*N2 + q0 + q)*32 + c]
                     + Ptheta[((size_t)(4 + b)*N2 + q0 + q)*32 + c]
                     + theta_b[c];
    }
    const float* Wsrc = br ? Wp_w : W_w;
    for (int u = tid; u < 2048; u += 576) {
        const int o = u >> 5, c = u & 31;
        Wt[c*64 + o] = Wsrc[u];
    }
    __syncthreads();

    // ---- phase 1: lane = key, 16 dots into Pt ----
    {
        const float* krow = Kp + ((size_t)bb*576 + tid)*32;
        float4 kf[8];
        #pragma unroll
        for (int i = 0; i < 8; ++i) kf[i] = ((const float4*)krow)[i];
        float s[16];
        #pragma unroll
        for (int q = 0; q < 16; ++q) {
            const float4* qr = (const float4*)&Qs[q*36];
            float a0 = 0.f, a1 = 0.f, a2 = 0.f, a3 = 0.f;
            #pragma unroll
            for (int i = 0; i < 8; ++i) {
                float4 qf = qr[i];
                a0 += qf.x*kf[i].x; a1 += qf.y*kf[i].y;
                a2 += qf.z*kf[i].z; a3 += qf.w*kf[i].w;
            }
            s[q] = (a0 + a1) + (a2 + a3);
        }
        #pragma unroll
        for (int q = 0; q < 16; ++q) Pt[q*580 + tid] = s[q];
    }
    __syncthreads();

    // ---- phase 1.5: exact softmax on Pt rows (256 threads) ----
    if (tid < 256) {
        const int q = tid >> 4, sl = tid & 15;
        float* row = &Pt[q*580 + 36*sl];
        float4 f[9];
        #pragma unroll
        for (int j = 0; j < 9; ++j) f[j] = *(const float4*)&row[4*j];
        float m = -1e30f;
        #pragma unroll
        for (int j = 0; j < 9; ++j)
            m = fmaxf(m, fmaxf(fmaxf(f[j].x, f[j].y), fmaxf(f[j].z, f[j].w)));
        m = fmaxf(m, __shfl_xor(m, 1));
        m = fmaxf(m, __shfl_xor(m, 2));
        m = fmaxf(m, __shfl_xor(m, 4));
        m = fmaxf(m, __shfl_xor(m, 8));
        float z = 0.f;
        #pragma unroll
        for (int j = 0; j < 9; ++j) {
            f[j].x = __expf(f[j].x - m); f[j].y = __expf(f[j].y - m);
            f[j].z = __expf(f[j].z - m); f[j].w = __expf(f[j].w - m);
            z += (f[j].x + f[j].y) + (f[j].z + f[j].w);
            *(float4*)&row[4*j] = f[j];
        }
        z += __shfl_xor(z, 1); z += __shfl_xor(z, 2);
        z += __shfl_xor(z, 4); z += __shfl_xor(z, 8);
        if (sl == 0) zinv[q] = 1.0f / z;
    }
    __syncthreads();

    // ---- phase 2: y[q][c] = (P . V[c]) * zinv (512 threads) ----
    if (tid < 512) {
        const int q = tid >> 5, c = tid & 31;
        const float* vrow = Vt + ((size_t)bb*32 + c)*576;
        const float* prow = &Pt[q*580];
        float a0 = 0.f, a1 = 0.f, a2 = 0.f, a3 = 0.f;
        #pragma unroll 4
        for (int kk = 0; kk < 144; ++kk) {
            float4 pa = *(const float4*)&prow[4*kk];
            float4 va = *(const float4*)&vrow[4*kk];
            a0 += pa.x*va.x; a1 += pa.y*va.y;
            a2 += pa.z*va.z; a3 += pa.w*va.w;
        }
        ybuf[q*36 + c] = ((a0 + a1) + (a2 + a3)) * zinv[q];
    }
    __syncthreads();

    // ---- phase 3: z = W.y + bias, store + BN partial stats ----
    if (tid < 512) {
        const int q = tid >> 5, o2 = tid & 31;
        const float* Wbias = br ? Wp_b : W_b;
        float z0a = 0.f, z0b = 0.f, z1a = 0.f, z1b = 0.f;
        #pragma unroll
        for (int c2 = 0; c2 < 32; c2 += 2) {
            float y0 = ybuf[q*36 + c2], y1 = ybuf[q*36 + c2 + 1];
            z0a += Wt[c2*64 + o2]*y0;        z0b += Wt[(c2+1)*64 + o2]*y1;
            z1a += Wt[c2*64 + o2 + 32]*y0;   z1b += Wt[(c2+1)*64 + o2 + 32]*y1;
        }
        float z0 = Wbias[o2]      + z0a + z0b;
        float z1 = Wbias[o2 + 32] + z1a + z1b;
        const int n = q0 + q;
        zbuf[((size_t)(br*64 + o2)*4 + b)*N2 + n]      = z0;
        zbuf[((size_t)(br*64 + o2 + 32)*4 + b)*N2 + n] = z1;
        float t0 = z0 + __shfl_xor(z0, 32);
        float t1 = z1 + __shfl_xor(z1, 32);
        float u0 = z0*z0; u0 += __shfl_xor(u0, 32);
        float u1 = z1*z1; u1 += __shfl_xor(u1, 32);
        if ((tid & 32) == 0) {
            const int w = tid >> 6;        // 0..7
            s1b[w*64 + o2]      = t0;  s1b[w*64 + o2 + 32] = t1;
            s2b[w*64 + o2]      = u0;  s2b[w*64 + o2 + 32] = u1;
        }
    }
    __syncthreads();
    if (tid < 64) {
        float ps = 0.f, pq = 0.f;
        #pragma unroll
        for (int w = 0; w < 8; ++w) { ps += s1b[w*64 + tid]; pq += s2b[w*64 + tid]; }
        Pp1[(size_t)(br*64 + tid)*576 + b*144 + qt] = ps;
        Pp2[(size_t)(br*64 + tid)*576 + b*144 + qt] = pq;
    }
}

// ---------------------------------------------------------------------------
// K4: BN stats from per-block partials (no atomics) + 2x2 nearest upsample.
// Grid (og 0..127, b 0..3), 576 threads.
// ---------------------------------------------------------------------------
__global__ __launch_bounds__(576) void bnup_kernel(
    const float* __restrict__ zbuf,
    const float* __restrict__ Pp1, const float* __restrict__ Pp2,
    const float* __restrict__ W_gamma, const float* __restrict__ W_beta,
    const float* __restrict__ Wp_gamma, const float* __restrict__ Wp_beta,
    float* __restrict__ out)
{
    const int og = blockIdx.x, b = blockIdx.y;
    const int br = og >> 6, o = og & 63;
    const int t = threadIdx.x;

    __shared__ float sb1[9], sb2[9], bc[2];
    float ps = Pp1[(size_t)og*576 + t];
    float pq = Pp2[(size_t)og*576 + t];
    #pragma unroll
    for (int d = 1; d < 64; d <<= 1) {
        ps += __shfl_xor(ps, d);
        pq += __shfl_xor(pq, d);
    }
    if ((t & 63) == 0) { sb1[t >> 6] = ps; sb2[t >> 6] = pq; }
    __syncthreads();
    if (t == 0) {
        float s = 0.f, qq = 0.f;
        #pragma unroll
        for (int w = 0; w < 9; ++w) { s += sb1[w]; qq += sb2[w]; }
        const float mean = s * (1.0f/9216.0f);
        const float var  = qq * (1.0f/9216.0f) - mean*mean;
        const float gamma = (br ? Wp_gamma : W_gamma)[o];
        const float beta  = (br ? Wp_beta  : W_beta)[o];
        const float scale = gamma * rsqrtf(var + 1e-5f);
        bc[0] = scale; bc[1] = beta - mean*scale;
    }
    __syncthreads();
    const float scale = bc[0], shift = bc[1];

    float4 a = *(const float4*)&zbuf[((size_t)og*4 + b)*N2 + 4*t];
    const int r = t / 12, cs = t % 12;
    float v0 = a.x*scale + shift, v1 = a.y*scale + shift;
    float v2 = a.z*scale + shift, v3 = a.w*scale + shift;
    float4 lo = {v0, v0, v1, v1};
    float4 hi = {v2, v2, v3, v3};
    float* ob = out + ((size_t)(b*128 + og)*96 + 2*r)*96 + 8*cs;
    *(float4*)(ob)       = lo;
    *(float4*)(ob + 4)   = hi;
    *(float4*)(ob + 96)  = lo;
    *(float4*)(ob + 100) = hi;
}

// ---------------------------------------------------------------------------
extern "C" void kernel_launch(void* const* d_in, const int* in_sizes, int n_in,
                              void* d_out, int out_size, void* d_ws, size_t ws_size,
                              hipStream_t stream) {
    (void)in_sizes; (void)n_in; (void)out_size; (void)ws_size;
    const float* x         = (const float*)d_in[0];
    const float* x_pan     = (const float*)d_in[1];
    const float* g_w       = (const float*)d_in[2];
    const float* g_b       = (const float*)d_in[3];
    const float* g_pan_w   = (const float*)d_in[4];
    const float* g_pan_b   = (const float*)d_in[5];
    const float* theta_w   = (const float*)d_in[6];
    const float* theta_b   = (const float*)d_in[7];
    const float* phi_w     = (const float*)d_in[8];
    const float* phi_b     = (const float*)d_in[9];
    const float* phi_pan_w = (const float*)d_in[10];
    const float* phi_pan_b = (const float*)d_in[11];
    const float* W_w       = (const float*)d_in[12];
    const float* W_b       = (const float*)d_in[13];
    const float* W_gamma   = (const float*)d_in[14];
    const float* W_beta    = (const float*)d_in[15];
    const float* Wp_w      = (const float*)d_in[16];
    const float* Wp_b      = (const float*)d_in[17];
    const float* Wp_gamma  = (const float*)d_in[18];
    const float* Wp_beta   = (const float*)d_in[19];

    float* out = (float*)d_out;
    float* ws  = (float*)d_ws;

    // workspace (floats), total 2,211,840 = 8.85 MB
    float* Ptheta = ws;                    // [2][4][2304][32]     = 589824
    float* Pphi   = Ptheta + 589824;       // [2][2][4][32][2304]  = 1179648
    float* zbuf   = Pphi;                  // alias: [128][4][2304] (Pphi dead)
    float* Kp     = Pphi + 1179648;        // [8][576][32] = 147456
    float* Vt     = Kp + 147456;           // [8][32][576] = 147456
    float* Pp1    = Vt + 147456;           // [128][576]   = 73728
    float* Pp2    = Pp1 + 73728;           // [128][576]   = 73728

    conv3x3_kernel<<<dim3(48, 4, 3), 128, 0, stream>>>(
        x, x_pan, theta_w, phi_w, phi_pan_w, Ptheta, Pphi);
    phipool_kernel<<<dim3(576), 256, 0, stream>>>(Pphi, phi_b, phi_pan_b, Kp);
    gconv_kernel<<<dim3(24, 2, 8), 384, 0, stream>>>(
        x, x_pan, g_w, g_b, g_pan_w, g_pan_b, Vt);
    attn_kernel<<<dim3(144, 8), 576, 0, stream>>>(
        Ptheta, theta_b, Kp, Vt, W_w, W_b, Wp_w, Wp_b, zbuf, Pp1, Pp2);
    bnup_kernel<<<dim3(128, 4), 576, 0, stream>>>(
        zbuf, Pp1, Pp2, W_gamma, W_beta, Wp_gamma, Wp_beta, out);
}